// Round 1
// baseline (521.907 us; speedup 1.0000x reference)
//
#include <hip/hip_runtime.h>
#include <hip/hip_bf16.h>

typedef __attribute__((ext_vector_type(8))) short short8;
typedef __attribute__((ext_vector_type(4))) float f32x4;

#define LOG2E 1.4426950408889634f

__device__ inline unsigned short f2b(float f){
  union { float f; unsigned int u; } a; a.f = f;
  unsigned int u = a.u;
  unsigned int r = (u + 0x7fff + ((u >> 16) & 1)) >> 16;
  return (unsigned short)r;
}

// ---------------- cast x -> bf16 ----------------
__global__ void k_cast_x(const float* __restrict__ x, unsigned short* __restrict__ xb, int n4){
  int i = blockIdx.x * blockDim.x + threadIdx.x;
  if (i < n4){
    float4 v = ((const float4*)x)[i];
    ushort4 o;
    o.x = f2b(v.x); o.y = f2b(v.y); o.z = f2b(v.z); o.w = f2b(v.w);
    ((ushort4*)xb)[i] = o;
  }
}

// ---------------- transpose + cast: in[R][Cc] f32 -> out[Cc][R] bf16 ----------------
__global__ void k_transpose_cast(const float* __restrict__ in, unsigned short* __restrict__ out,
                                 int R, int Cc){
  __shared__ float tile[32][33];
  int bx = blockIdx.x, by = blockIdx.y;
  int tx = threadIdx.x, ty = threadIdx.y;
  int col = bx*32 + tx;
  #pragma unroll
  for (int jj = 0; jj < 4; ++jj){
    int row = by*32 + ty + jj*8;
    tile[ty + jj*8][tx] = in[(size_t)row*Cc + col];
  }
  __syncthreads();
  int r = by*32 + tx;
  #pragma unroll
  for (int jj = 0; jj < 4; ++jj){
    int c = bx*32 + ty + jj*8;
    out[(size_t)c*R + r] = f2b(tile[tx][ty + jj*8]);
  }
}

// ---------------- GEMM: C = A[M][K] * Bt[N][K]^T + bias ----------------
// MODE 0: scatter to q/k/v bf16 buffers [B,H,T,hd], Q scaled by 0.125
// MODE 1: fp32 output [M][N]
template<int MODE>
__global__ __launch_bounds__(256) void k_gemm_bt(
    const unsigned short* __restrict__ A,
    const unsigned short* __restrict__ Bt,
    const float* __restrict__ bias,
    float* __restrict__ Cout,
    unsigned short* __restrict__ qb,
    unsigned short* __restrict__ kbf,
    unsigned short* __restrict__ vbf,
    int Mdim, int Ndim, int Kdim)
{
  __shared__ alignas(16) unsigned short As[128*40];
  __shared__ alignas(16) unsigned short Bs[128*40];
  const int tid  = threadIdx.x;
  const int lane = tid & 63;
  const int wid  = tid >> 6;
  const int wm   = wid >> 1, wn = wid & 1;
  const int bn   = blockIdx.x, bm = blockIdx.y;
  const int l15  = lane & 15, lhi = lane >> 4;

  f32x4 acc[4][4] = {};

  const int rowA0 = bm * 128, rowB0 = bn * 128;
  const int r0  = tid >> 2;          // 0..63
  const int kc0 = (tid & 3) * 8;     // 0,8,16,24

  const int nK = Kdim >> 5;
  for (int kt = 0; kt < nK; ++kt){
    const int kofs = kt*32 + kc0;
    short8 a0 = *(const short8*)(A  + (size_t)(rowA0 + r0)      * Kdim + kofs);
    short8 a1 = *(const short8*)(A  + (size_t)(rowA0 + r0 + 64) * Kdim + kofs);
    short8 b0 = *(const short8*)(Bt + (size_t)(rowB0 + r0)      * Kdim + kofs);
    short8 b1 = *(const short8*)(Bt + (size_t)(rowB0 + r0 + 64) * Kdim + kofs);
    __syncthreads();
    *(short8*)(As + (r0)    *40 + kc0) = a0;
    *(short8*)(As + (r0+64) *40 + kc0) = a1;
    *(short8*)(Bs + (r0)    *40 + kc0) = b0;
    *(short8*)(Bs + (r0+64) *40 + kc0) = b1;
    __syncthreads();
    short8 af[4], bf[4];
    #pragma unroll
    for (int f = 0; f < 4; ++f){
      af[f] = *(const short8*)(As + (wm*64 + f*16 + l15)*40 + lhi*8);
      bf[f] = *(const short8*)(Bs + (wn*64 + f*16 + l15)*40 + lhi*8);
    }
    #pragma unroll
    for (int fm = 0; fm < 4; ++fm)
      #pragma unroll
      for (int fn = 0; fn < 4; ++fn)
        acc[fm][fn] = __builtin_amdgcn_mfma_f32_16x16x32_bf16(af[fm], bf[fn], acc[fm][fn], 0, 0, 0);
  }

  #pragma unroll
  for (int fm = 0; fm < 4; ++fm){
    #pragma unroll
    for (int fn = 0; fn < 4; ++fn){
      #pragma unroll
      for (int j = 0; j < 4; ++j){
        int m = bm*128 + wm*64 + fm*16 + lhi*4 + j;
        int n = bn*128 + wn*64 + fn*16 + l15;
        float v = acc[fm][fn][j] + bias[n];
        if (MODE == 0){
          int which = n >> 10; int cc2 = n & 1023; int h = cc2 >> 6; int d = cc2 & 63;
          int bb = m >> 11;    int t = m & 2047;
          if (which == 0) v *= 0.125f;   // fold 1/sqrt(64) into Q
          unsigned short* dst = (which == 0) ? qb : ((which == 1) ? kbf : vbf);
          dst[(size_t)((bb*16 + h)*2048 + t)*64 + d] = f2b(v);
        } else {
          Cout[(size_t)m * Ndim + n] = v;
        }
      }
    }
  }
}

// ---------------- causal flash attention ----------------
// grid: (T/64, B*H), block 256 (4 waves x 16 q-rows each)
__global__ __launch_bounds__(256) void k_attn(
    const unsigned short* __restrict__ qb,
    const unsigned short* __restrict__ kbuf,
    const unsigned short* __restrict__ vbuf,
    unsigned short* __restrict__ ao)
{
  __shared__ alignas(16) unsigned short P_lds[4*16*72];
  __shared__ alignas(16) unsigned short Vt_lds[64*72];
  const int tid  = threadIdx.x;
  const int lane = tid & 63, wid = tid >> 6;
  const int l15  = lane & 15, lhi = lane >> 4;
  const int qt   = blockIdx.x, bh = blockIdx.y;
  const int q0w  = qt*64 + wid*16;
  const size_t base = (size_t)bh * 2048 * 64;

  short8 qf[2];
  #pragma unroll
  for (int i = 0; i < 2; ++i)
    qf[i] = *(const short8*)(qb + base + (size_t)(q0w + l15)*64 + i*32 + lhi*8);

  float m_run[4] = {-1e30f, -1e30f, -1e30f, -1e30f};
  float l_run[4] = {0.f, 0.f, 0.f, 0.f};
  f32x4 o_acc[4] = {};

  const int nkt = qt + 1;
  for (int kt = 0; kt < nkt; ++kt){
    const int kb0 = kt*64;
    // ---- S = Q K^T (Q pre-scaled) ----
    f32x4 s[4] = {};
    #pragma unroll
    for (int fn = 0; fn < 4; ++fn){
      #pragma unroll
      for (int i = 0; i < 2; ++i){
        short8 kf = *(const short8*)(kbuf + base + (size_t)(kb0 + fn*16 + l15)*64 + i*32 + lhi*8);
        s[fn] = __builtin_amdgcn_mfma_f32_16x16x32_bf16(qf[i], kf, s[fn], 0, 0, 0);
      }
    }
    // ---- causal mask ----
    #pragma unroll
    for (int fn = 0; fn < 4; ++fn){
      #pragma unroll
      for (int j = 0; j < 4; ++j){
        int qi = q0w + lhi*4 + j;
        int ki = kb0 + fn*16 + l15;
        if (ki > qi) s[fn][j] = -1e30f;
      }
    }
    // ---- online softmax (per q-row = 16-lane group reduce) ----
    float p[4][4];
    #pragma unroll
    for (int j = 0; j < 4; ++j){
      float v = fmaxf(fmaxf(s[0][j], s[1][j]), fmaxf(s[2][j], s[3][j]));
      v = fmaxf(v, __shfl_xor(v, 1));
      v = fmaxf(v, __shfl_xor(v, 2));
      v = fmaxf(v, __shfl_xor(v, 4));
      v = fmaxf(v, __shfl_xor(v, 8));
      float mn = fmaxf(m_run[j], v);
      float corr = exp2f((m_run[j] - mn) * LOG2E);
      m_run[j] = mn;
      float r = 0.f;
      #pragma unroll
      for (int fn = 0; fn < 4; ++fn){
        float e = exp2f((s[fn][j] - mn) * LOG2E);
        p[fn][j] = e;
        r += e;
      }
      r += __shfl_xor(r, 1); r += __shfl_xor(r, 2);
      r += __shfl_xor(r, 4); r += __shfl_xor(r, 8);
      l_run[j] = l_run[j]*corr + r;
      #pragma unroll
      for (int df = 0; df < 4; ++df) o_acc[df][j] *= corr;
    }
    // ---- write P (bf16) to LDS in A-frag source layout ----
    unsigned short* Pw = P_lds + wid*16*72;
    #pragma unroll
    for (int fn = 0; fn < 4; ++fn)
      #pragma unroll
      for (int j = 0; j < 4; ++j)
        Pw[(lhi*4 + j)*72 + fn*16 + l15] = f2b(p[fn][j]);
    // ---- stage V^T tile cooperatively ----
    {
      int kk = tid >> 2;          // 0..63
      int d0 = (tid & 3) * 16;
      const unsigned short* vsrc = vbuf + base + (size_t)(kb0 + kk)*64 + d0;
      short8 v0 = *(const short8*)(vsrc);
      short8 v1 = *(const short8*)(vsrc + 8);
      #pragma unroll
      for (int i = 0; i < 8; ++i) Vt_lds[(d0 + i)*72 + kk]     = (unsigned short)v0[i];
      #pragma unroll
      for (int i = 0; i < 8; ++i) Vt_lds[(d0 + 8 + i)*72 + kk] = (unsigned short)v1[i];
    }
    __syncthreads();
    // ---- O += P V ----
    short8 pa[2];
    #pragma unroll
    for (int i = 0; i < 2; ++i)
      pa[i] = *(const short8*)(P_lds + wid*16*72 + l15*72 + i*32 + lhi*8);
    #pragma unroll
    for (int df = 0; df < 4; ++df){
      #pragma unroll
      for (int i = 0; i < 2; ++i){
        short8 vf = *(const short8*)(Vt_lds + (df*16 + l15)*72 + i*32 + lhi*8);
        o_acc[df] = __builtin_amdgcn_mfma_f32_16x16x32_bf16(pa[i], vf, o_acc[df], 0, 0, 0);
      }
    }
    __syncthreads();
  }
  // ---- normalize + write [B,T,H*hd] bf16 ----
  const int b = bh >> 4, h = bh & 15;
  #pragma unroll
  for (int df = 0; df < 4; ++df){
    #pragma unroll
    for (int j = 0; j < 4; ++j){
      int qrow = q0w + lhi*4 + j;
      float v = o_acc[df][j] / l_run[j];
      ao[(size_t)(b*2048 + qrow)*1024 + h*64 + df*16 + l15] = f2b(v);
    }
  }
}

extern "C" void kernel_launch(void* const* d_in, const int* in_sizes, int n_in,
                              void* d_out, int out_size, void* d_ws, size_t ws_size,
                              hipStream_t stream){
  const float* x     = (const float*)d_in[0];
  const float* Wqkv  = (const float*)d_in[1];
  const float* bqkv  = (const float*)d_in[2];
  const float* Wproj = (const float*)d_in[3];
  const float* bproj = (const float*)d_in[4];
  float* out = (float*)d_out;

  unsigned short* ws     = (unsigned short*)d_ws;
  unsigned short* xb     = ws;                       // 8192*1024
  unsigned short* wqkvT  = xb + 8388608;             // 3072*1024
  unsigned short* wprojT = wqkvT + 3145728;          // 1024*1024
  unsigned short* qbuf   = wprojT + 1048576;         // [B,H,T,64]
  unsigned short* kbuf   = qbuf + 8388608;
  unsigned short* vbuf   = kbuf + 8388608;
  unsigned short* ao     = vbuf + 8388608;           // [B,T,1024]

  k_cast_x<<<8192, 256, 0, stream>>>(x, xb, 2097152);
  k_transpose_cast<<<dim3(96, 32), dim3(32, 8), 0, stream>>>(Wqkv, wqkvT, 1024, 3072);
  k_transpose_cast<<<dim3(32, 32), dim3(32, 8), 0, stream>>>(Wproj, wprojT, 1024, 1024);
  k_gemm_bt<0><<<dim3(24, 64), 256, 0, stream>>>(xb, wqkvT, bqkv, nullptr,
                                                 qbuf, kbuf, vbuf, 8192, 3072, 1024);
  k_attn<<<dim3(32, 64), 256, 0, stream>>>(qbuf, kbuf, vbuf, ao);
  k_gemm_bt<1><<<dim3(8, 64), 256, 0, stream>>>(ao, wprojT, bproj, out,
                                                nullptr, nullptr, nullptr, 8192, 1024, 1024);
}